// Round 4
// baseline (8885.102 us; speedup 1.0000x reference)
//
#include <hip/hip_runtime.h>
#include <cstdint>
#include <cstddef>

typedef float    float4v __attribute__((ext_vector_type(4)));
typedef _Float16 f16x4   __attribute__((ext_vector_type(4)));
typedef _Float16 f16x8   __attribute__((ext_vector_type(8)));

#define DI __device__ __forceinline__

static const int Bsz = 64, Tlen = 2048, Hd = 128, G4 = 512;  // 4H=512
static const int Mrows = Bsz * Tlen;                          // 131072
static const int HSTR = 136;   // padded H row stride (f16): bank-safe, validated R3
static const int GPAD = 516;   // padded gates row stride (f32): 516*4B, 16B-aligned

DI float sigf_fast(float x) {
    float e = __builtin_amdgcn_exp2f(-1.442695041f * x);
    return __builtin_amdgcn_rcpf(1.f + e);
}
DI float tanhf_fast(float x) {
    float e = __builtin_amdgcn_exp2f(-2.885390082f * x);
    return 2.f * __builtin_amdgcn_rcpf(1.f + e) - 1.f;
}

// load 8 consecutive f32, convert to f16x8
DI f16x8 cvt8(const float* p) {
    float4v u = *(const float4v*)p;
    float4v w = *(const float4v*)(p + 4);
    f16x8 o;
    o[0] = (_Float16)u[0]; o[1] = (_Float16)u[1]; o[2] = (_Float16)u[2]; o[3] = (_Float16)u[3];
    o[4] = (_Float16)w[0]; o[5] = (_Float16)w[1]; o[6] = (_Float16)w[2]; o[7] = (_Float16)w[3];
    return o;
}

// ---------------------------------------------------------------------------
// GEMM: C[M,N] = A[M,128] @ Wsel^T (+bias). MFMA f32_16x16x32_f16.
// blockIdx.x = n-block (fastest) so all N-blocks of one A-tile are
// co-resident -> A read once from HBM, rest from L2.
// PERM: output col n pulls W row ((n&3)*128 + (n>>2)) so XP is stored
// gate-interleaved (n' = 4j+q), f16. !PERM: plain, f32 out + bias.
// Validated layout contracts from R2/R3.
// ---------------------------------------------------------------------------
template <bool A_F16, bool PERM, bool OUT_F32>
__global__ __launch_bounds__(256) void gemm_k128(
    const void* __restrict__ Av, const float* __restrict__ W,
    const float* __restrict__ bias, void* __restrict__ Cout, int M, int N)
{
    const int lane = threadIdx.x & 63, wave = threadIdx.x >> 6;
    const int m0 = blockIdx.y * 64 + wave * 16;
    const int n0 = blockIdx.x * 64;
    const int r15 = lane & 15, kg = lane >> 4;   // kg in 0..3

    f16x8 a[4];
    if (A_F16) {
        const f16x8* Ar = (const f16x8*)((const _Float16*)Av + (size_t)(m0 + r15) * 128);
#pragma unroll
        for (int kt = 0; kt < 4; kt++) a[kt] = Ar[kt * 4 + kg];
    } else {
        const float* Ar = (const float*)Av + (size_t)(m0 + r15) * 128;
#pragma unroll
        for (int kt = 0; kt < 4; kt++) a[kt] = cvt8(Ar + kt * 32 + kg * 8);
    }

    f16x8 bfrg[4][4];
#pragma unroll
    for (int nt = 0; nt < 4; nt++) {
        int n = n0 + nt * 16 + r15;
        int wrow = PERM ? ((n & 3) * 128 + (n >> 2)) : n;
        const float* Wr = W + (size_t)wrow * 128;
#pragma unroll
        for (int kt = 0; kt < 4; kt++) bfrg[nt][kt] = cvt8(Wr + kt * 32 + kg * 8);
    }

    float4v acc[4] = {};
#pragma unroll
    for (int kt = 0; kt < 4; kt++)
#pragma unroll
        for (int nt = 0; nt < 4; nt++)
            acc[nt] = __builtin_amdgcn_mfma_f32_16x16x32_f16(a[kt], bfrg[nt][kt], acc[nt], 0, 0, 0);

#pragma unroll
    for (int nt = 0; nt < 4; nt++) {
        int n = n0 + nt * 16 + r15;
        float bv = bias ? bias[n] : 0.f;
#pragma unroll
        for (int r = 0; r < 4; r++) {
            int m = m0 + kg * 4 + r;
            float v = acc[nt][r] + bv;
            if (OUT_F32) ((float*)Cout)[(size_t)m * N + n] = v;
            else         ((_Float16*)Cout)[(size_t)m * N + n] = (_Float16)v;
        }
    }
}

// ---------------------------------------------------------------------------
// LSTM recurrence v2. 16 WGs x 256 threads (4 waves); NB=4 batches/WG.
// Gate-interleaved m-permutation: MFMA m-tile row m = 4*jj + q, so lane
// (col b=r15<4, quad) ends with acc[mt][q] = the 4 gates of ONE (b,j).
// Whh A-frags static in VGPRs (8 m-tiles x 4 kc). Per step:
//   bf: 4 ds_read_b128/wave from H[cur] (HSTR=136, bank-safe)
//   32 MFMA/wave (128/CU ~= 512 cyc, the step floor)
//   lanes r15<4 store float4 gates -> Gl[b][4j..] (GPAD=516, conflict-free)
//   barrier; 256 threads x 2 (b,j) pairs: f32x4 Gl read + bias + xp(8B, from
//   the PERMuted XP) + 10 transcendentals; h -> H[nxt] (ping-pong); barrier.
// ---------------------------------------------------------------------------
template <bool HAS_XP, bool WRITE_Y, bool INIT>
__global__ __launch_bounds__(256, 1) void lstm_rec2(
    const float* __restrict__ U,                     // Whh [512,128] f32
    const float* __restrict__ bi, const float* __restrict__ bh,
    const _Float16* __restrict__ XP,                 // [B,T,512] f16 PERMUTED (4j+q)
    const float* __restrict__ ih, const float* __restrict__ ic,
    _Float16* __restrict__ Yout,                     // [B,T,128] f16 or null
    float* __restrict__ fh, float* __restrict__ fc, int T)
{
    const int tid  = threadIdx.x;
    const int lane = tid & 63, w = tid >> 6;         // 4 waves
    const int r15  = lane & 15, quad = lane >> 4;
    const int bbase = blockIdx.x * 4;

    __shared__ alignas(16) _Float16 Hl[2 * 16 * HSTR];   // ping-pong h (rows 4..15 stay 0)
    __shared__ alignas(16) float    Gl[4 * GPAD];        // gates, interleaved 4j+q

    // --- static A-frags: tile mt covers j in [w*32+mt*4, +4); tile-row m=r15
    //     maps to Whh row (m&3)*128 + (w*32 + mt*4 + (m>>2)) ---
    f16x8 af[8][4];
#pragma unroll
    for (int mt = 0; mt < 8; mt++) {
        int urow = (r15 & 3) * 128 + (w * 32 + mt * 4 + (r15 >> 2));
        const float* ur = U + (size_t)urow * 128;
#pragma unroll
        for (int kc = 0; kc < 4; kc++)
            af[mt][kc] = cvt8(ur + kc * 32 + quad * 8);
    }

    // --- update-role mapping: pairs (bA, j) and (bA+2, j) ---
    const int j  = tid & 127;
    const int bA = tid >> 7;                          // 0..1
    float bq[4];
#pragma unroll
    for (int q = 0; q < 4; q++) bq[q] = bi[q * 128 + j] + bh[q * 128 + j];

    for (int i = tid; i < 2 * 16 * HSTR; i += 256) Hl[i] = (_Float16)0.f;
    __syncthreads();

    float cA = 0.f, hA = 0.f, cB = 0.f, hB = 0.f;
    if (INIT) {
        cA = ic[(size_t)(bbase + bA) * 128 + j];
        hA = ih[(size_t)(bbase + bA) * 128 + j];
        cB = ic[(size_t)(bbase + bA + 2) * 128 + j];
        hB = ih[(size_t)(bbase + bA + 2) * 128 + j];
    }
    Hl[bA * HSTR + j]       = (_Float16)hA;
    Hl[(bA + 2) * HSTR + j] = (_Float16)hB;
    __syncthreads();

    const _Float16* xbaseA = HAS_XP ? XP + ((size_t)(bbase + bA) * T) * 512 + 4 * j : nullptr;
    const _Float16* xbaseB = HAS_XP ? XP + ((size_t)(bbase + bA + 2) * T) * 512 + 4 * j : nullptr;
    f16x4 xpA = {}, xpB = {};
    if (HAS_XP) { xpA = *(const f16x4*)xbaseA; xpB = *(const f16x4*)xbaseB; }

    int cur = 0;
    for (int t = 0; t < T; t++) {
        // ---- MFMA phase ----
        const _Float16* Hc = Hl + cur * (16 * HSTR);
        f16x8 bf[4];
#pragma unroll
        for (int kc = 0; kc < 4; kc++)
            bf[kc] = *(const f16x8*)(Hc + r15 * HSTR + kc * 32 + quad * 8);

        float4v acc[8] = {};
#pragma unroll
        for (int kc = 0; kc < 4; kc++)
#pragma unroll
            for (int mt = 0; mt < 8; mt++)
                acc[mt] = __builtin_amdgcn_mfma_f32_16x16x32_f16(af[mt][kc], bf[kc], acc[mt], 0, 0, 0);

        if (r15 < 4) {
#pragma unroll
            for (int mt = 0; mt < 8; mt++)
                *(float4v*)(Gl + (size_t)r15 * GPAD + (w * 32 + mt * 4 + quad) * 4) = acc[mt];
        }
        __syncthreads();

        // ---- update phase ----
        f16x4 xpAn = {}, xpBn = {};
        if (HAS_XP && (t + 1 < T)) {
            xpAn = *(const f16x4*)(xbaseA + (size_t)(t + 1) * 512);
            xpBn = *(const f16x4*)(xbaseB + (size_t)(t + 1) * 512);
        }

        float4v gA = *(const float4v*)(Gl + (size_t)bA * GPAD + 4 * j);
        float4v gB = *(const float4v*)(Gl + (size_t)(bA + 2) * GPAD + 4 * j);

        float g0 = gA[0] + bq[0], g1 = gA[1] + bq[1], g2 = gA[2] + bq[2], g3 = gA[3] + bq[3];
        if (HAS_XP) { g0 += (float)xpA[0]; g1 += (float)xpA[1]; g2 += (float)xpA[2]; g3 += (float)xpA[3]; }
        {
            float iv = sigf_fast(g0), fv = sigf_fast(g1);
            float gv = tanhf_fast(g2), ov = sigf_fast(g3);
            cA = fv * cA + iv * gv;
            hA = ov * tanhf_fast(cA);
        }
        float k0 = gB[0] + bq[0], k1 = gB[1] + bq[1], k2 = gB[2] + bq[2], k3 = gB[3] + bq[3];
        if (HAS_XP) { k0 += (float)xpB[0]; k1 += (float)xpB[1]; k2 += (float)xpB[2]; k3 += (float)xpB[3]; }
        {
            float iv = sigf_fast(k0), fv = sigf_fast(k1);
            float gv = tanhf_fast(k2), ov = sigf_fast(k3);
            cB = fv * cB + iv * gv;
            hB = ov * tanhf_fast(cB);
        }

        _Float16* Hn = Hl + (cur ^ 1) * (16 * HSTR);
        Hn[bA * HSTR + j]       = (_Float16)hA;
        Hn[(bA + 2) * HSTR + j] = (_Float16)hB;
        if (WRITE_Y) {
            Yout[((size_t)(bbase + bA) * T + t) * 128 + j]     = (_Float16)hA;
            Yout[((size_t)(bbase + bA + 2) * T + t) * 128 + j] = (_Float16)hB;
        }
        __syncthreads();

        xpA = xpAn; xpB = xpBn;
        cur ^= 1;
    }

    fh[(size_t)(bbase + bA) * 128 + j]       = hA;
    fc[(size_t)(bbase + bA) * 128 + j]       = cA;
    fh[(size_t)(bbase + bA + 2) * 128 + j]   = hB;
    fc[(size_t)(bbase + bA + 2) * 128 + j]   = cB;
}

// ---------------------------------------------------------------------------
// Host side: 8 stream-ordered launches.
//   ws: XP f16 [131072,512] perm (128MB) | Y f16 [131072,128] (32MB) | finals
// ---------------------------------------------------------------------------
extern "C" void kernel_launch(void* const* d_in, const int* in_sizes, int n_in,
                              void* d_out, int out_size, void* d_ws, size_t ws_size,
                              hipStream_t stream)
{
    const float* x    = (const float*)d_in[0];
    const float* eW0  = (const float*)d_in[1];
    const float* eU0  = (const float*)d_in[2];
    const float* eb0i = (const float*)d_in[3];
    const float* eb0h = (const float*)d_in[4];
    const float* eW1  = (const float*)d_in[5];
    const float* eU1  = (const float*)d_in[6];
    const float* eb1i = (const float*)d_in[7];
    const float* eb1h = (const float*)d_in[8];
    const float* dU0  = (const float*)d_in[10];
    const float* db0i = (const float*)d_in[11];
    const float* db0h = (const float*)d_in[12];
    const float* dW1  = (const float*)d_in[13];
    const float* dU1  = (const float*)d_in[14];
    const float* db1i = (const float*)d_in[15];
    const float* db1h = (const float*)d_in[16];
    const float* oW   = (const float*)d_in[17];
    const float* ob   = (const float*)d_in[18];

    char* ws = (char*)d_ws;
    _Float16* XP = (_Float16*)ws;                               // 134217728 B
    _Float16* Y  = (_Float16*)(ws + 134217728);                 //  33554432 B
    float*    fh0 = (float*)(ws + 167772160);
    float*    fc0 = fh0 + Bsz * Hd;
    float*    fh1 = fc0 + Bsz * Hd;
    float*    fc1 = fh1 + Bsz * Hd;

    dim3 blk(256);
    dim3 gXP(G4 / 64, Mrows / 64);    // (8, 2048): n-block fastest
    dim3 gOut(Hd / 64, Mrows / 64);   // (2, 2048)
    dim3 rgrid(Bsz / 4);              // 16
    dim3 rblk(256);

    // 1) XP = x @ enc_Wih0^T (permuted, f16)
    gemm_k128<false, true, false><<<gXP, blk, 0, stream>>>((const void*)x, eW0, (const float*)nullptr, (void*)XP, Mrows, G4);
    // 2) enc L0
    lstm_rec2<true, true, false><<<rgrid, rblk, 0, stream>>>(
        eU0, eb0i, eb0h, XP, (const float*)nullptr, (const float*)nullptr, Y, fh0, fc0, Tlen);
    // 3) XP = y0 @ enc_Wih1^T (permuted)
    gemm_k128<true, true, false><<<gXP, blk, 0, stream>>>((const void*)Y, eW1, (const float*)nullptr, (void*)XP, Mrows, G4);
    // 4) enc L1 (y discarded)
    lstm_rec2<true, false, false><<<rgrid, rblk, 0, stream>>>(
        eU1, eb1i, eb1h, XP, (const float*)nullptr, (const float*)nullptr, (_Float16*)nullptr, fh1, fc1, Tlen);
    // 5) dec L0: zeros input, init (fh0,fc0)
    lstm_rec2<false, true, true><<<rgrid, rblk, 0, stream>>>(
        dU0, db0i, db0h, (const _Float16*)nullptr, fh0, fc0, Y, fh0, fc0, Tlen);
    // 6) XP = d0 @ dec_Wih1^T (permuted)
    gemm_k128<true, true, false><<<gXP, blk, 0, stream>>>((const void*)Y, dW1, (const float*)nullptr, (void*)XP, Mrows, G4);
    // 7) dec L1: init (fh1,fc1)
    lstm_rec2<true, true, true><<<rgrid, rblk, 0, stream>>>(
        dU1, db1i, db1h, XP, fh1, fc1, Y, fh1, fc1, Tlen);
    // 8) out = d1 @ out_W^T + out_b (f32 -> d_out)
    gemm_k128<true, false, true><<<gOut, blk, 0, stream>>>((const void*)Y, oW, ob, d_out, Mrows, Hd);
}

// Round 5
// 7348.824 us; speedup vs baseline: 1.2091x; 1.2091x over previous
//
#include <hip/hip_runtime.h>
#include <cstdint>
#include <cstddef>

typedef float    float4v __attribute__((ext_vector_type(4)));
typedef _Float16 f16x4   __attribute__((ext_vector_type(4)));
typedef _Float16 f16x8   __attribute__((ext_vector_type(8)));

#define DI __device__ __forceinline__

static const int Bsz = 64, Tlen = 2048, Hd = 128, G4 = 512;  // 4H=512
static const int Mrows = Bsz * Tlen;                          // 131072
static const int HSTR = 136;   // padded H row stride (f16): bank-safe, validated R3/R4
static const int GPAD = 516;   // padded gates row stride (f32): 16B-aligned

DI float sigf_fast(float x) {
    float e = __builtin_amdgcn_exp2f(-1.442695041f * x);
    return __builtin_amdgcn_rcpf(1.f + e);
}
DI float tanhf_fast(float x) {
    float e = __builtin_amdgcn_exp2f(-2.885390082f * x);
    return 2.f * __builtin_amdgcn_rcpf(1.f + e) - 1.f;
}

// Workgroup barrier that orders LDS only (lgkmcnt), NOT outstanding global
// loads/stores (vmcnt). __syncthreads() would emit s_waitcnt vmcnt(0) before
// s_barrier, draining the per-step xp prefetch / Y stores on the critical
// path (the R2-R4 ~1400cyc/step stall). All data exchanged across this
// barrier lives in LDS; global traffic here is wave-private.
DI void lds_barrier() {
    asm volatile("s_waitcnt lgkmcnt(0)\n\ts_barrier" ::: "memory");
}

// load 8 consecutive f32, convert to f16x8
DI f16x8 cvt8(const float* p) {
    float4v u = *(const float4v*)p;
    float4v w = *(const float4v*)(p + 4);
    f16x8 o;
    o[0] = (_Float16)u[0]; o[1] = (_Float16)u[1]; o[2] = (_Float16)u[2]; o[3] = (_Float16)u[3];
    o[4] = (_Float16)w[0]; o[5] = (_Float16)w[1]; o[6] = (_Float16)w[2]; o[7] = (_Float16)w[3];
    return o;
}

// ---------------------------------------------------------------------------
// GEMM: C[M,N] = A[M,128] @ Wsel^T (+bias). MFMA f32_16x16x32_f16.
// n-block fastest -> A-tile read once from HBM, re-hit in L2.
// PERM: col n pulls W row ((n&3)*128 + (n>>2)) -> XP gate-interleaved (4j+q).
// Validated R4.
// ---------------------------------------------------------------------------
template <bool A_F16, bool PERM, bool OUT_F32>
__global__ __launch_bounds__(256) void gemm_k128(
    const void* __restrict__ Av, const float* __restrict__ W,
    const float* __restrict__ bias, void* __restrict__ Cout, int M, int N)
{
    const int lane = threadIdx.x & 63, wave = threadIdx.x >> 6;
    const int m0 = blockIdx.y * 64 + wave * 16;
    const int n0 = blockIdx.x * 64;
    const int r15 = lane & 15, kg = lane >> 4;   // kg in 0..3

    f16x8 a[4];
    if (A_F16) {
        const f16x8* Ar = (const f16x8*)((const _Float16*)Av + (size_t)(m0 + r15) * 128);
#pragma unroll
        for (int kt = 0; kt < 4; kt++) a[kt] = Ar[kt * 4 + kg];
    } else {
        const float* Ar = (const float*)Av + (size_t)(m0 + r15) * 128;
#pragma unroll
        for (int kt = 0; kt < 4; kt++) a[kt] = cvt8(Ar + kt * 32 + kg * 8);
    }

    f16x8 bfrg[4][4];
#pragma unroll
    for (int nt = 0; nt < 4; nt++) {
        int n = n0 + nt * 16 + r15;
        int wrow = PERM ? ((n & 3) * 128 + (n >> 2)) : n;
        const float* Wr = W + (size_t)wrow * 128;
#pragma unroll
        for (int kt = 0; kt < 4; kt++) bfrg[nt][kt] = cvt8(Wr + kt * 32 + kg * 8);
    }

    float4v acc[4] = {};
#pragma unroll
    for (int kt = 0; kt < 4; kt++)
#pragma unroll
        for (int nt = 0; nt < 4; nt++)
            acc[nt] = __builtin_amdgcn_mfma_f32_16x16x32_f16(a[kt], bfrg[nt][kt], acc[nt], 0, 0, 0);

#pragma unroll
    for (int nt = 0; nt < 4; nt++) {
        int n = n0 + nt * 16 + r15;
        float bv = bias ? bias[n] : 0.f;
#pragma unroll
        for (int r = 0; r < 4; r++) {
            int m = m0 + kg * 4 + r;
            float v = acc[nt][r] + bv;
            if (OUT_F32) ((float*)Cout)[(size_t)m * N + n] = v;
            else         ((_Float16*)Cout)[(size_t)m * N + n] = (_Float16)v;
        }
    }
}

// ---------------------------------------------------------------------------
// LSTM recurrence v3 = R4's v2 + lds_barrier (no vmcnt drain) + early
// xp prefetch. 16 WGs x 256 threads; NB=4 batches/WG.
// Gate-interleaved m-permutation: lane (col b=r15<4, quad) ends with
// acc[mt][q] = the 4 gates of ONE (b, j=w*32+mt*4+quad).
// ---------------------------------------------------------------------------
template <bool HAS_XP, bool WRITE_Y, bool INIT>
__global__ __launch_bounds__(256, 1) void lstm_rec2(
    const float* __restrict__ U,                     // Whh [512,128] f32
    const float* __restrict__ bi, const float* __restrict__ bh,
    const _Float16* __restrict__ XP,                 // [B,T,512] f16 PERMUTED (4j+q)
    const float* __restrict__ ih, const float* __restrict__ ic,
    _Float16* __restrict__ Yout,                     // [B,T,128] f16 or null
    float* __restrict__ fh, float* __restrict__ fc, int T)
{
    const int tid  = threadIdx.x;
    const int lane = tid & 63, w = tid >> 6;         // 4 waves
    const int r15  = lane & 15, quad = lane >> 4;
    const int bbase = blockIdx.x * 4;

    __shared__ alignas(16) _Float16 Hl[2 * 16 * HSTR];   // ping-pong h (rows 4..15 stay 0)
    __shared__ alignas(16) float    Gl[4 * GPAD];        // gates, interleaved 4j+q

    // --- static A-frags: tile-row m=r15 -> Whh row (m&3)*128 + (w*32+mt*4+(m>>2)) ---
    f16x8 af[8][4];
#pragma unroll
    for (int mt = 0; mt < 8; mt++) {
        int urow = (r15 & 3) * 128 + (w * 32 + mt * 4 + (r15 >> 2));
        const float* ur = U + (size_t)urow * 128;
#pragma unroll
        for (int kc = 0; kc < 4; kc++)
            af[mt][kc] = cvt8(ur + kc * 32 + quad * 8);
    }

    // --- update-role mapping: pairs (bA, j) and (bA+2, j) ---
    const int j  = tid & 127;
    const int bA = tid >> 7;                          // 0..1
    float bq[4];
#pragma unroll
    for (int q = 0; q < 4; q++) bq[q] = bi[q * 128 + j] + bh[q * 128 + j];

    for (int i = tid; i < 2 * 16 * HSTR; i += 256) Hl[i] = (_Float16)0.f;
    __syncthreads();

    float cA = 0.f, hA = 0.f, cB = 0.f, hB = 0.f;
    if (INIT) {
        cA = ic[(size_t)(bbase + bA) * 128 + j];
        hA = ih[(size_t)(bbase + bA) * 128 + j];
        cB = ic[(size_t)(bbase + bA + 2) * 128 + j];
        hB = ih[(size_t)(bbase + bA + 2) * 128 + j];
    }
    Hl[bA * HSTR + j]       = (_Float16)hA;
    Hl[(bA + 2) * HSTR + j] = (_Float16)hB;
    __syncthreads();

    const _Float16* xbaseA = HAS_XP ? XP + ((size_t)(bbase + bA) * T) * 512 + 4 * j : nullptr;
    const _Float16* xbaseB = HAS_XP ? XP + ((size_t)(bbase + bA + 2) * T) * 512 + 4 * j : nullptr;
    f16x4 xpA = {}, xpB = {};
    if (HAS_XP) { xpA = *(const f16x4*)xbaseA; xpB = *(const f16x4*)xbaseB; }

    int cur = 0;
    for (int t = 0; t < T; t++) {
        // ---- prefetch xp(t+1) EARLY: in flight across the whole step ----
        f16x4 xpAn = {}, xpBn = {};
        if (HAS_XP && (t + 1 < T)) {
            xpAn = *(const f16x4*)(xbaseA + (size_t)(t + 1) * 512);
            xpBn = *(const f16x4*)(xbaseB + (size_t)(t + 1) * 512);
        }

        // ---- MFMA phase ----
        const _Float16* Hc = Hl + cur * (16 * HSTR);
        f16x8 bf[4];
#pragma unroll
        for (int kc = 0; kc < 4; kc++)
            bf[kc] = *(const f16x8*)(Hc + r15 * HSTR + kc * 32 + quad * 8);

        float4v acc[8] = {};
#pragma unroll
        for (int kc = 0; kc < 4; kc++)
#pragma unroll
            for (int mt = 0; mt < 8; mt++)
                acc[mt] = __builtin_amdgcn_mfma_f32_16x16x32_f16(af[mt][kc], bf[kc], acc[mt], 0, 0, 0);

        if (r15 < 4) {
#pragma unroll
            for (int mt = 0; mt < 8; mt++)
                *(float4v*)(Gl + (size_t)r15 * GPAD + (w * 32 + mt * 4 + quad) * 4) = acc[mt];
        }
        lds_barrier();                                // gates visible; LDS-only

        // ---- update phase ----
        float4v gA = *(const float4v*)(Gl + (size_t)bA * GPAD + 4 * j);
        float4v gB = *(const float4v*)(Gl + (size_t)(bA + 2) * GPAD + 4 * j);

        float g0 = gA[0] + bq[0], g1 = gA[1] + bq[1], g2 = gA[2] + bq[2], g3 = gA[3] + bq[3];
        if (HAS_XP) { g0 += (float)xpA[0]; g1 += (float)xpA[1]; g2 += (float)xpA[2]; g3 += (float)xpA[3]; }
        {
            float iv = sigf_fast(g0), fv = sigf_fast(g1);
            float gv = tanhf_fast(g2), ov = sigf_fast(g3);
            cA = fv * cA + iv * gv;
            hA = ov * tanhf_fast(cA);
        }
        float k0 = gB[0] + bq[0], k1 = gB[1] + bq[1], k2 = gB[2] + bq[2], k3 = gB[3] + bq[3];
        if (HAS_XP) { k0 += (float)xpB[0]; k1 += (float)xpB[1]; k2 += (float)xpB[2]; k3 += (float)xpB[3]; }
        {
            float iv = sigf_fast(k0), fv = sigf_fast(k1);
            float gv = tanhf_fast(k2), ov = sigf_fast(k3);
            cB = fv * cB + iv * gv;
            hB = ov * tanhf_fast(cB);
        }

        _Float16* Hn = Hl + (cur ^ 1) * (16 * HSTR);
        Hn[bA * HSTR + j]       = (_Float16)hA;
        Hn[(bA + 2) * HSTR + j] = (_Float16)hB;
        if (WRITE_Y) {
            Yout[((size_t)(bbase + bA) * T + t) * 128 + j]     = (_Float16)hA;
            Yout[((size_t)(bbase + bA + 2) * T + t) * 128 + j] = (_Float16)hB;
        }
        lds_barrier();                                // new h visible; LDS-only

        xpA = xpAn; xpB = xpBn;
        cur ^= 1;
    }

    fh[(size_t)(bbase + bA) * 128 + j]       = hA;
    fc[(size_t)(bbase + bA) * 128 + j]       = cA;
    fh[(size_t)(bbase + bA + 2) * 128 + j]   = hB;
    fc[(size_t)(bbase + bA + 2) * 128 + j]   = cB;
}

// ---------------------------------------------------------------------------
// Host side: 8 stream-ordered launches.
//   ws: XP f16 [131072,512] perm (128MB) | Y f16 [131072,128] (32MB) | finals
// ---------------------------------------------------------------------------
extern "C" void kernel_launch(void* const* d_in, const int* in_sizes, int n_in,
                              void* d_out, int out_size, void* d_ws, size_t ws_size,
                              hipStream_t stream)
{
    const float* x    = (const float*)d_in[0];
    const float* eW0  = (const float*)d_in[1];
    const float* eU0  = (const float*)d_in[2];
    const float* eb0i = (const float*)d_in[3];
    const float* eb0h = (const float*)d_in[4];
    const float* eW1  = (const float*)d_in[5];
    const float* eU1  = (const float*)d_in[6];
    const float* eb1i = (const float*)d_in[7];
    const float* eb1h = (const float*)d_in[8];
    const float* dU0  = (const float*)d_in[10];
    const float* db0i = (const float*)d_in[11];
    const float* db0h = (const float*)d_in[12];
    const float* dW1  = (const float*)d_in[13];
    const float* dU1  = (const float*)d_in[14];
    const float* db1i = (const float*)d_in[15];
    const float* db1h = (const float*)d_in[16];
    const float* oW   = (const float*)d_in[17];
    const float* ob   = (const float*)d_in[18];

    char* ws = (char*)d_ws;
    _Float16* XP = (_Float16*)ws;                               // 134217728 B
    _Float16* Y  = (_Float16*)(ws + 134217728);                 //  33554432 B
    float*    fh0 = (float*)(ws + 167772160);
    float*    fc0 = fh0 + Bsz * Hd;
    float*    fh1 = fc0 + Bsz * Hd;
    float*    fc1 = fh1 + Bsz * Hd;

    dim3 blk(256);
    dim3 gXP(G4 / 64, Mrows / 64);    // (8, 2048): n-block fastest
    dim3 gOut(Hd / 64, Mrows / 64);   // (2, 2048)
    dim3 rgrid(Bsz / 4);              // 16
    dim3 rblk(256);

    // 1) XP = x @ enc_Wih0^T (permuted, f16)
    gemm_k128<false, true, false><<<gXP, blk, 0, stream>>>((const void*)x, eW0, (const float*)nullptr, (void*)XP, Mrows, G4);
    // 2) enc L0
    lstm_rec2<true, true, false><<<rgrid, rblk, 0, stream>>>(
        eU0, eb0i, eb0h, XP, (const float*)nullptr, (const float*)nullptr, Y, fh0, fc0, Tlen);
    // 3) XP = y0 @ enc_Wih1^T (permuted)
    gemm_k128<true, true, false><<<gXP, blk, 0, stream>>>((const void*)Y, eW1, (const float*)nullptr, (void*)XP, Mrows, G4);
    // 4) enc L1 (y discarded)
    lstm_rec2<true, false, false><<<rgrid, rblk, 0, stream>>>(
        eU1, eb1i, eb1h, XP, (const float*)nullptr, (const float*)nullptr, (_Float16*)nullptr, fh1, fc1, Tlen);
    // 5) dec L0: zeros input, init (fh0,fc0)
    lstm_rec2<false, true, true><<<rgrid, rblk, 0, stream>>>(
        dU0, db0i, db0h, (const _Float16*)nullptr, fh0, fc0, Y, fh0, fc0, Tlen);
    // 6) XP = d0 @ dec_Wih1^T (permuted)
    gemm_k128<true, true, false><<<gXP, blk, 0, stream>>>((const void*)Y, dW1, (const float*)nullptr, (void*)XP, Mrows, G4);
    // 7) dec L1: init (fh1,fc1)
    lstm_rec2<true, true, true><<<rgrid, rblk, 0, stream>>>(
        dU1, db1i, db1h, XP, fh1, fc1, Y, fh1, fc1, Tlen);
    // 8) out = d1 @ out_W^T + out_b (f32 -> d_out)
    gemm_k128<true, false, true><<<gOut, blk, 0, stream>>>((const void*)Y, oW, ob, d_out, Mrows, Hd);
}

// Round 6
// 6573.895 us; speedup vs baseline: 1.3516x; 1.1179x over previous
//
#include <hip/hip_runtime.h>
#include <cstdint>
#include <cstddef>

typedef float    float4v __attribute__((ext_vector_type(4)));
typedef _Float16 f16x4   __attribute__((ext_vector_type(4)));
typedef _Float16 f16x8   __attribute__((ext_vector_type(8)));

#define DI __device__ __forceinline__

static const int Bsz = 64, Tlen = 2048, Hd = 128, G4 = 512;  // 4H=512
static const int Mrows = Bsz * Tlen;                          // 131072
static const int HSTR = 136;   // padded H row stride (f16), validated R3-R5

DI float sigf_fast(float x) {
    float e = __builtin_amdgcn_exp2f(-1.442695041f * x);
    return __builtin_amdgcn_rcpf(1.f + e);
}
DI float tanhf_fast(float x) {
    float e = __builtin_amdgcn_exp2f(-2.885390082f * x);
    return 2.f * __builtin_amdgcn_rcpf(1.f + e) - 1.f;
}

// LDS-only barrier: no vmcnt drain (validated R5, -24%).
DI void lds_barrier() {
    asm volatile("s_waitcnt lgkmcnt(0)\n\ts_barrier" ::: "memory");
}

// load 8 consecutive f32, convert to f16x8
DI f16x8 cvt8(const float* p) {
    float4v u = *(const float4v*)p;
    float4v w = *(const float4v*)(p + 4);
    f16x8 o;
    o[0] = (_Float16)u[0]; o[1] = (_Float16)u[1]; o[2] = (_Float16)u[2]; o[3] = (_Float16)u[3];
    o[4] = (_Float16)w[0]; o[5] = (_Float16)w[1]; o[6] = (_Float16)w[2]; o[7] = (_Float16)w[3];
    return o;
}

// ---------------------------------------------------------------------------
// GEMM: C[M,N] = A[M,128] @ Wsel^T (+bias). MFMA f32_16x16x32_f16.
// n-block fastest -> A-tile read once from HBM, re-hit in L2.
// PERM: col n pulls W row ((n&3)*128 + (n>>2)) -> XP gate-interleaved (4j+q).
// Validated R4/R5.
// ---------------------------------------------------------------------------
template <bool A_F16, bool PERM, bool OUT_F32>
__global__ __launch_bounds__(256) void gemm_k128(
    const void* __restrict__ Av, const float* __restrict__ W,
    const float* __restrict__ bias, void* __restrict__ Cout, int M, int N)
{
    const int lane = threadIdx.x & 63, wave = threadIdx.x >> 6;
    const int m0 = blockIdx.y * 64 + wave * 16;
    const int n0 = blockIdx.x * 64;
    const int r15 = lane & 15, kg = lane >> 4;   // kg in 0..3

    f16x8 a[4];
    if (A_F16) {
        const f16x8* Ar = (const f16x8*)((const _Float16*)Av + (size_t)(m0 + r15) * 128);
#pragma unroll
        for (int kt = 0; kt < 4; kt++) a[kt] = Ar[kt * 4 + kg];
    } else {
        const float* Ar = (const float*)Av + (size_t)(m0 + r15) * 128;
#pragma unroll
        for (int kt = 0; kt < 4; kt++) a[kt] = cvt8(Ar + kt * 32 + kg * 8);
    }

    f16x8 bfrg[4][4];
#pragma unroll
    for (int nt = 0; nt < 4; nt++) {
        int n = n0 + nt * 16 + r15;
        int wrow = PERM ? ((n & 3) * 128 + (n >> 2)) : n;
        const float* Wr = W + (size_t)wrow * 128;
#pragma unroll
        for (int kt = 0; kt < 4; kt++) bfrg[nt][kt] = cvt8(Wr + kt * 32 + kg * 8);
    }

    float4v acc[4] = {};
#pragma unroll
    for (int kt = 0; kt < 4; kt++)
#pragma unroll
        for (int nt = 0; nt < 4; nt++)
            acc[nt] = __builtin_amdgcn_mfma_f32_16x16x32_f16(a[kt], bfrg[nt][kt], acc[nt], 0, 0, 0);

#pragma unroll
    for (int nt = 0; nt < 4; nt++) {
        int n = n0 + nt * 16 + r15;
        float bv = bias ? bias[n] : 0.f;
#pragma unroll
        for (int r = 0; r < 4; r++) {
            int m = m0 + kg * 4 + r;
            float v = acc[nt][r] + bv;
            if (OUT_F32) ((float*)Cout)[(size_t)m * N + n] = v;
            else         ((_Float16*)Cout)[(size_t)m * N + n] = (_Float16)v;
        }
    }
}

// ---------------------------------------------------------------------------
// LSTM recurrence v4. 16 WGs x 256 threads; NB=4 batches/WG.
// B-columns replicated: B[n][k] = h[n&3][k] (same-address LDS reads =
// broadcast, free). Every lane (col=b+4s, quad) then holds VALID gates:
// acc[mt][q] = gate q of (b, j=w*32+mt*4+quad). Copy s consumes mt=2s,2s+1
// (cndmask select) -> 2 gate-sets per thread IN REGISTERS. No gates LDS
// round-trip, no second barrier: ONE lds_barrier per step.
// H ping-pong: 4 rows x HSTR f16; every (b,j) owned by exactly one thread.
// ---------------------------------------------------------------------------
template <bool HAS_XP, bool WRITE_Y, bool INIT>
__global__ __launch_bounds__(256, 1) void lstm_rec4(
    const float* __restrict__ U,                     // Whh [512,128] f32
    const float* __restrict__ bi, const float* __restrict__ bh,
    const _Float16* __restrict__ XP,                 // [B,T,512] f16 PERMUTED (4j+q)
    const float* __restrict__ ih, const float* __restrict__ ic,
    _Float16* __restrict__ Yout,                     // [B,T,128] f16 or null
    float* __restrict__ fh, float* __restrict__ fc, int T)
{
    const int tid  = threadIdx.x;
    const int lane = tid & 63, w = tid >> 6;         // 4 waves
    const int col  = lane & 15, quad = lane >> 4;
    const int b    = col & 3, s = col >> 2;          // batch, copy id
    const int bglob = blockIdx.x * 4 + b;
    const int jA = w * 32 + (2 * s) * 4 + quad;      // owned gate-sets
    const int jB = jA + 4;

    __shared__ alignas(16) _Float16 Hl[2 * 4 * HSTR];

    // --- static A-frags (verified R4/R5): tile-row m=col ->
    //     Whh row (m&3)*128 + (w*32 + mt*4 + (m>>2)) ---
    f16x8 af[8][4];
#pragma unroll
    for (int mt = 0; mt < 8; mt++) {
        int urow = (col & 3) * 128 + (w * 32 + mt * 4 + (col >> 2));
        const float* ur = U + (size_t)urow * 128;
#pragma unroll
        for (int kc = 0; kc < 4; kc++)
            af[mt][kc] = cvt8(ur + kc * 32 + quad * 8);
    }

    float bqA[4], bqB[4];
#pragma unroll
    for (int q = 0; q < 4; q++) {
        bqA[q] = bi[q * 128 + jA] + bh[q * 128 + jA];
        bqB[q] = bi[q * 128 + jB] + bh[q * 128 + jB];
    }

    float cA = 0.f, hA = 0.f, cB = 0.f, hB = 0.f;
    if (INIT) {
        cA = ic[(size_t)bglob * 128 + jA]; hA = ih[(size_t)bglob * 128 + jA];
        cB = ic[(size_t)bglob * 128 + jB]; hB = ih[(size_t)bglob * 128 + jB];
    }
    Hl[b * HSTR + jA] = (_Float16)hA;                // every (b,j) covered once
    Hl[b * HSTR + jB] = (_Float16)hB;
    __syncthreads();

    const _Float16* xbA = HAS_XP ? XP + ((size_t)bglob * T) * 512 + 4 * jA : nullptr;
    const _Float16* xbB = HAS_XP ? XP + ((size_t)bglob * T) * 512 + 4 * jB : nullptr;
    f16x4 xpA = {}, xpB = {};
    if (HAS_XP) { xpA = *(const f16x4*)xbA; xpB = *(const f16x4*)xbB; }

    int cur = 0;
    for (int t = 0; t < T; t++) {
        // prefetch xp(t+1): in flight across the whole step
        f16x4 xpAn = {}, xpBn = {};
        if (HAS_XP && (t + 1 < T)) {
            xpAn = *(const f16x4*)(xbA + (size_t)(t + 1) * 512);
            xpBn = *(const f16x4*)(xbB + (size_t)(t + 1) * 512);
        }

        // ---- MFMA phase: B replicated by batch (row b for all 4 copies) ----
        const _Float16* Hc = Hl + cur * (4 * HSTR);
        f16x8 bf[4];
#pragma unroll
        for (int kc = 0; kc < 4; kc++)
            bf[kc] = *(const f16x8*)(Hc + b * HSTR + kc * 32 + quad * 8);

        float4v acc[8] = {};
#pragma unroll
        for (int kc = 0; kc < 4; kc++)
#pragma unroll
            for (int mt = 0; mt < 8; mt++)
                acc[mt] = __builtin_amdgcn_mfma_f32_16x16x32_f16(af[mt][kc], bf[kc], acc[mt], 0, 0, 0);

        // ---- select this lane's 2 gate-sets: mt = 2s and 2s+1 ----
        float4v gx = (s & 1) ? acc[2] : acc[0];
        float4v gy = (s & 1) ? acc[6] : acc[4];
        float4v gA = (s & 2) ? gy : gx;
        float4v hx = (s & 1) ? acc[3] : acc[1];
        float4v hy = (s & 1) ? acc[7] : acc[5];
        float4v gB = (s & 2) ? hy : hx;

        // ---- update in registers ----
        float g0 = gA[0] + bqA[0], g1 = gA[1] + bqA[1], g2 = gA[2] + bqA[2], g3 = gA[3] + bqA[3];
        if (HAS_XP) { g0 += (float)xpA[0]; g1 += (float)xpA[1]; g2 += (float)xpA[2]; g3 += (float)xpA[3]; }
        {
            float iv = sigf_fast(g0), fv = sigf_fast(g1);
            float gv = tanhf_fast(g2), ov = sigf_fast(g3);
            cA = fv * cA + iv * gv;
            hA = ov * tanhf_fast(cA);
        }
        float k0 = gB[0] + bqB[0], k1 = gB[1] + bqB[1], k2 = gB[2] + bqB[2], k3 = gB[3] + bqB[3];
        if (HAS_XP) { k0 += (float)xpB[0]; k1 += (float)xpB[1]; k2 += (float)xpB[2]; k3 += (float)xpB[3]; }
        {
            float iv = sigf_fast(k0), fv = sigf_fast(k1);
            float gv = tanhf_fast(k2), ov = sigf_fast(k3);
            cB = fv * cB + iv * gv;
            hB = ov * tanhf_fast(cB);
        }

        _Float16* Hn = Hl + (cur ^ 1) * (4 * HSTR);
        Hn[b * HSTR + jA] = (_Float16)hA;
        Hn[b * HSTR + jB] = (_Float16)hB;
        if (WRITE_Y) {
            Yout[((size_t)bglob * T + t) * 128 + jA] = (_Float16)hA;
            Yout[((size_t)bglob * T + t) * 128 + jB] = (_Float16)hB;
        }
        lds_barrier();                                // ONE barrier per step

        xpA = xpAn; xpB = xpBn;
        cur ^= 1;
    }

    fh[(size_t)bglob * 128 + jA] = hA;
    fc[(size_t)bglob * 128 + jA] = cA;
    fh[(size_t)bglob * 128 + jB] = hB;
    fc[(size_t)bglob * 128 + jB] = cB;
}

// ---------------------------------------------------------------------------
// Host side: 8 stream-ordered launches.
//   ws: XP f16 [131072,512] perm (128MB) | Y f16 [131072,128] (32MB) | finals
// ---------------------------------------------------------------------------
extern "C" void kernel_launch(void* const* d_in, const int* in_sizes, int n_in,
                              void* d_out, int out_size, void* d_ws, size_t ws_size,
                              hipStream_t stream)
{
    const float* x    = (const float*)d_in[0];
    const float* eW0  = (const float*)d_in[1];
    const float* eU0  = (const float*)d_in[2];
    const float* eb0i = (const float*)d_in[3];
    const float* eb0h = (const float*)d_in[4];
    const float* eW1  = (const float*)d_in[5];
    const float* eU1  = (const float*)d_in[6];
    const float* eb1i = (const float*)d_in[7];
    const float* eb1h = (const float*)d_in[8];
    const float* dU0  = (const float*)d_in[10];
    const float* db0i = (const float*)d_in[11];
    const float* db0h = (const float*)d_in[12];
    const float* dW1  = (const float*)d_in[13];
    const float* dU1  = (const float*)d_in[14];
    const float* db1i = (const float*)d_in[15];
    const float* db1h = (const float*)d_in[16];
    const float* oW   = (const float*)d_in[17];
    const float* ob   = (const float*)d_in[18];

    char* ws = (char*)d_ws;
    _Float16* XP = (_Float16*)ws;                               // 134217728 B
    _Float16* Y  = (_Float16*)(ws + 134217728);                 //  33554432 B
    float*    fh0 = (float*)(ws + 167772160);
    float*    fc0 = fh0 + Bsz * Hd;
    float*    fh1 = fc0 + Bsz * Hd;
    float*    fc1 = fh1 + Bsz * Hd;

    dim3 blk(256);
    dim3 gXP(G4 / 64, Mrows / 64);    // (8, 2048): n-block fastest
    dim3 gOut(Hd / 64, Mrows / 64);   // (2, 2048)
    dim3 rgrid(Bsz / 4);              // 16
    dim3 rblk(256);

    // 1) XP = x @ enc_Wih0^T (permuted, f16)
    gemm_k128<false, true, false><<<gXP, blk, 0, stream>>>((const void*)x, eW0, (const float*)nullptr, (void*)XP, Mrows, G4);
    // 2) enc L0
    lstm_rec4<true, true, false><<<rgrid, rblk, 0, stream>>>(
        eU0, eb0i, eb0h, XP, (const float*)nullptr, (const float*)nullptr, Y, fh0, fc0, Tlen);
    // 3) XP = y0 @ enc_Wih1^T (permuted)
    gemm_k128<true, true, false><<<gXP, blk, 0, stream>>>((const void*)Y, eW1, (const float*)nullptr, (void*)XP, Mrows, G4);
    // 4) enc L1 (y discarded)
    lstm_rec4<true, false, false><<<rgrid, rblk, 0, stream>>>(
        eU1, eb1i, eb1h, XP, (const float*)nullptr, (const float*)nullptr, (_Float16*)nullptr, fh1, fc1, Tlen);
    // 5) dec L0: zeros input, init (fh0,fc0)
    lstm_rec4<false, true, true><<<rgrid, rblk, 0, stream>>>(
        dU0, db0i, db0h, (const _Float16*)nullptr, fh0, fc0, Y, fh0, fc0, Tlen);
    // 6) XP = d0 @ dec_Wih1^T (permuted)
    gemm_k128<true, true, false><<<gXP, blk, 0, stream>>>((const void*)Y, dW1, (const float*)nullptr, (void*)XP, Mrows, G4);
    // 7) dec L1: init (fh1,fc1)
    lstm_rec4<true, true, true><<<rgrid, rblk, 0, stream>>>(
        dU1, db1i, db1h, XP, fh1, fc1, Y, fh1, fc1, Tlen);
    // 8) out = d1 @ out_W^T + out_b (f32 -> d_out)
    gemm_k128<true, false, true><<<gOut, blk, 0, stream>>>((const void*)Y, oW, ob, d_out, Mrows, Hd);
}

// Round 7
// 6021.310 us; speedup vs baseline: 1.4756x; 1.0918x over previous
//
#include <hip/hip_runtime.h>
#include <cstdint>
#include <cstddef>

typedef float    float4v __attribute__((ext_vector_type(4)));
typedef _Float16 f16x4   __attribute__((ext_vector_type(4)));
typedef _Float16 f16x8   __attribute__((ext_vector_type(8)));

#define DI __device__ __forceinline__

static const int Bsz = 64, Tlen = 2048, Hd = 128, G4 = 512;  // 4H=512
static const int Mrows = Bsz * Tlen;                          // 131072
static const int HSTR = 144;   // H row stride (f16): 72 dwords = 8 mod 32 ->
                               // the 16 (b,quad) bf-read addrs cover 32 banks 2-way (free)

DI float sigf_fast(float x) {
    float e = __builtin_amdgcn_exp2f(-1.442695041f * x);
    return __builtin_amdgcn_rcpf(1.f + e);
}
DI float tanhf_fast(float x) {
    float e = __builtin_amdgcn_exp2f(-2.885390082f * x);
    return 2.f * __builtin_amdgcn_rcpf(1.f + e) - 1.f;
}

// LDS-only barrier: no vmcnt drain (validated R5, -24%).
DI void lds_barrier() {
    asm volatile("s_waitcnt lgkmcnt(0)\n\ts_barrier" ::: "memory");
}

// load 8 consecutive f32, convert to f16x8
DI f16x8 cvt8(const float* p) {
    float4v u = *(const float4v*)p;
    float4v w = *(const float4v*)(p + 4);
    f16x8 o;
    o[0] = (_Float16)u[0]; o[1] = (_Float16)u[1]; o[2] = (_Float16)u[2]; o[3] = (_Float16)u[3];
    o[4] = (_Float16)w[0]; o[5] = (_Float16)w[1]; o[6] = (_Float16)w[2]; o[7] = (_Float16)w[3];
    return o;
}

// ---------------------------------------------------------------------------
// GEMM: C[M,N] = A[M,128] @ Wsel^T (+bias). MFMA f32_16x16x32_f16.
// n-block fastest -> A-tile read once from HBM, re-hit in L2.
// PERM: col n pulls W row ((n&3)*128 + (n>>2)) -> XP gate-interleaved (4j+q).
// Validated R4-R6.
// ---------------------------------------------------------------------------
template <bool A_F16, bool PERM, bool OUT_F32>
__global__ __launch_bounds__(256) void gemm_k128(
    const void* __restrict__ Av, const float* __restrict__ W,
    const float* __restrict__ bias, void* __restrict__ Cout, int M, int N)
{
    const int lane = threadIdx.x & 63, wave = threadIdx.x >> 6;
    const int m0 = blockIdx.y * 64 + wave * 16;
    const int n0 = blockIdx.x * 64;
    const int r15 = lane & 15, kg = lane >> 4;   // kg in 0..3

    f16x8 a[4];
    if (A_F16) {
        const f16x8* Ar = (const f16x8*)((const _Float16*)Av + (size_t)(m0 + r15) * 128);
#pragma unroll
        for (int kt = 0; kt < 4; kt++) a[kt] = Ar[kt * 4 + kg];
    } else {
        const float* Ar = (const float*)Av + (size_t)(m0 + r15) * 128;
#pragma unroll
        for (int kt = 0; kt < 4; kt++) a[kt] = cvt8(Ar + kt * 32 + kg * 8);
    }

    f16x8 bfrg[4][4];
#pragma unroll
    for (int nt = 0; nt < 4; nt++) {
        int n = n0 + nt * 16 + r15;
        int wrow = PERM ? ((n & 3) * 128 + (n >> 2)) : n;
        const float* Wr = W + (size_t)wrow * 128;
#pragma unroll
        for (int kt = 0; kt < 4; kt++) bfrg[nt][kt] = cvt8(Wr + kt * 32 + kg * 8);
    }

    float4v acc[4] = {};
#pragma unroll
    for (int kt = 0; kt < 4; kt++)
#pragma unroll
        for (int nt = 0; nt < 4; nt++)
            acc[nt] = __builtin_amdgcn_mfma_f32_16x16x32_f16(a[kt], bfrg[nt][kt], acc[nt], 0, 0, 0);

#pragma unroll
    for (int nt = 0; nt < 4; nt++) {
        int n = n0 + nt * 16 + r15;
        float bv = bias ? bias[n] : 0.f;
#pragma unroll
        for (int r = 0; r < 4; r++) {
            int m = m0 + kg * 4 + r;
            float v = acc[nt][r] + bv;
            if (OUT_F32) ((float*)Cout)[(size_t)m * N + n] = v;
            else         ((_Float16*)Cout)[(size_t)m * N + n] = (_Float16)v;
        }
    }
}

// ---------------------------------------------------------------------------
// LSTM recurrence v5. 16 WGs x 512 threads (8 waves, 2/SIMD); NB=4.
// Same verified dataflow as v4 but j-range halved per wave:
//   wave w owns j in [16w,16w+16): 4 m-tiles x 4 kc = 16 MFMA/wave.
//   A-frag: tile-row m=col -> Whh row (m&3)*128 + (w*16 + mt*4 + (m>>2)).
//   B replicated: B[n][k] = h[n&3][k] (same-addr LDS broadcast, free).
//   Lane (col=b+4s, quad): acc[mt][q] = gate q of (b, j=w*16+mt*4+quad);
//   its OWN gate-set is mt=s -> one-level select, ONE gate-set per thread.
// 2 waves/SIMD => the other wave's MFMA (matrix pipe) overlaps this wave's
// update (VALU/trans pipe) - m114. ONE lds_barrier/step.
// ---------------------------------------------------------------------------
template <bool HAS_XP, bool WRITE_Y, bool INIT>
__global__ __launch_bounds__(512, 1) void lstm_rec5(
    const float* __restrict__ U,                     // Whh [512,128] f32
    const float* __restrict__ bi, const float* __restrict__ bh,
    const _Float16* __restrict__ XP,                 // [B,T,512] f16 PERMUTED (4j+q)
    const float* __restrict__ ih, const float* __restrict__ ic,
    _Float16* __restrict__ Yout,                     // [B,T,128] f16 or null
    float* __restrict__ fh, float* __restrict__ fc, int T)
{
    const int tid  = threadIdx.x;
    const int lane = tid & 63, w = tid >> 6;         // 8 waves
    const int col  = lane & 15, quad = lane >> 4;
    const int b    = col & 3, s = col >> 2;          // batch, copy id
    const int bglob = blockIdx.x * 4 + b;
    const int j    = w * 16 + s * 4 + quad;          // owned gate-set (unique per thread)

    __shared__ alignas(16) _Float16 Hl[2 * 4 * HSTR];

    // --- static A-frags: tile-row m=col -> Whh row (m&3)*128 + (w*16+mt*4+(m>>2)) ---
    f16x8 af[4][4];
#pragma unroll
    for (int mt = 0; mt < 4; mt++) {
        int urow = (col & 3) * 128 + (w * 16 + mt * 4 + (col >> 2));
        const float* ur = U + (size_t)urow * 128;
#pragma unroll
        for (int kc = 0; kc < 4; kc++)
            af[mt][kc] = cvt8(ur + kc * 32 + quad * 8);
    }

    float bq[4];
#pragma unroll
    for (int q = 0; q < 4; q++) bq[q] = bi[q * 128 + j] + bh[q * 128 + j];

    float c = 0.f, hv = 0.f;
    if (INIT) {
        c  = ic[(size_t)bglob * 128 + j];
        hv = ih[(size_t)bglob * 128 + j];
    }
    Hl[b * HSTR + j] = (_Float16)hv;                 // every (b,j) covered exactly once
    __syncthreads();

    const _Float16* xb = HAS_XP ? XP + ((size_t)bglob * T) * 512 + 4 * j : nullptr;
    f16x4 xp = {};
    if (HAS_XP) xp = *(const f16x4*)xb;

    int cur = 0;
    for (int t = 0; t < T; t++) {
        // prefetch xp(t+1): in flight across the whole step
        f16x4 xpn = {};
        if (HAS_XP && (t + 1 < T)) xpn = *(const f16x4*)(xb + (size_t)(t + 1) * 512);

        // ---- MFMA phase: B replicated by batch (row b for all 4 copies) ----
        const _Float16* Hc = Hl + cur * (4 * HSTR);
        f16x8 bf[4];
#pragma unroll
        for (int kc = 0; kc < 4; kc++)
            bf[kc] = *(const f16x8*)(Hc + b * HSTR + kc * 32 + quad * 8);

        float4v acc[4] = {};
#pragma unroll
        for (int kc = 0; kc < 4; kc++)
#pragma unroll
            for (int mt = 0; mt < 4; mt++)
                acc[mt] = __builtin_amdgcn_mfma_f32_16x16x32_f16(af[mt][kc], bf[kc], acc[mt], 0, 0, 0);

        // ---- select this lane's gate-set: mt = s ----
        float4v t0 = (s & 1) ? acc[1] : acc[0];
        float4v t1 = (s & 1) ? acc[3] : acc[2];
        float4v g  = (s & 2) ? t1 : t0;

        // ---- update in registers ----
        float g0 = g[0] + bq[0], g1 = g[1] + bq[1], g2 = g[2] + bq[2], g3 = g[3] + bq[3];
        if (HAS_XP) { g0 += (float)xp[0]; g1 += (float)xp[1]; g2 += (float)xp[2]; g3 += (float)xp[3]; }
        float iv = sigf_fast(g0), fv = sigf_fast(g1);
        float gv = tanhf_fast(g2), ov = sigf_fast(g3);
        c  = fv * c + iv * gv;
        hv = ov * tanhf_fast(c);

        Hl[(cur ^ 1) * (4 * HSTR) + b * HSTR + j] = (_Float16)hv;
        if (WRITE_Y)
            Yout[((size_t)bglob * T + t) * 128 + j] = (_Float16)hv;
        lds_barrier();                                // ONE barrier per step

        xp = xpn;
        cur ^= 1;
    }

    fh[(size_t)bglob * 128 + j] = hv;
    fc[(size_t)bglob * 128 + j] = c;
}

// ---------------------------------------------------------------------------
// Host side: 8 stream-ordered launches.
//   ws: XP f16 [131072,512] perm (128MB) | Y f16 [131072,128] (32MB) | finals
// ---------------------------------------------------------------------------
extern "C" void kernel_launch(void* const* d_in, const int* in_sizes, int n_in,
                              void* d_out, int out_size, void* d_ws, size_t ws_size,
                              hipStream_t stream)
{
    const float* x    = (const float*)d_in[0];
    const float* eW0  = (const float*)d_in[1];
    const float* eU0  = (const float*)d_in[2];
    const float* eb0i = (const float*)d_in[3];
    const float* eb0h = (const float*)d_in[4];
    const float* eW1  = (const float*)d_in[5];
    const float* eU1  = (const float*)d_in[6];
    const float* eb1i = (const float*)d_in[7];
    const float* eb1h = (const float*)d_in[8];
    const float* dU0  = (const float*)d_in[10];
    const float* db0i = (const float*)d_in[11];
    const float* db0h = (const float*)d_in[12];
    const float* dW1  = (const float*)d_in[13];
    const float* dU1  = (const float*)d_in[14];
    const float* db1i = (const float*)d_in[15];
    const float* db1h = (const float*)d_in[16];
    const float* oW   = (const float*)d_in[17];
    const float* ob   = (const float*)d_in[18];

    char* ws = (char*)d_ws;
    _Float16* XP = (_Float16*)ws;                               // 134217728 B
    _Float16* Y  = (_Float16*)(ws + 134217728);                 //  33554432 B
    float*    fh0 = (float*)(ws + 167772160);
    float*    fc0 = fh0 + Bsz * Hd;
    float*    fh1 = fc0 + Bsz * Hd;
    float*    fc1 = fh1 + Bsz * Hd;

    dim3 blk(256);
    dim3 gXP(G4 / 64, Mrows / 64);    // (8, 2048): n-block fastest
    dim3 gOut(Hd / 64, Mrows / 64);   // (2, 2048)
    dim3 rgrid(Bsz / 4);              // 16
    dim3 rblk(512);

    // 1) XP = x @ enc_Wih0^T (permuted, f16)
    gemm_k128<false, true, false><<<gXP, blk, 0, stream>>>((const void*)x, eW0, (const float*)nullptr, (void*)XP, Mrows, G4);
    // 2) enc L0
    lstm_rec5<true, true, false><<<rgrid, rblk, 0, stream>>>(
        eU0, eb0i, eb0h, XP, (const float*)nullptr, (const float*)nullptr, Y, fh0, fc0, Tlen);
    // 3) XP = y0 @ enc_Wih1^T (permuted)
    gemm_k128<true, true, false><<<gXP, blk, 0, stream>>>((const void*)Y, eW1, (const float*)nullptr, (void*)XP, Mrows, G4);
    // 4) enc L1 (y discarded)
    lstm_rec5<true, false, false><<<rgrid, rblk, 0, stream>>>(
        eU1, eb1i, eb1h, XP, (const float*)nullptr, (const float*)nullptr, (_Float16*)nullptr, fh1, fc1, Tlen);
    // 5) dec L0: zeros input, init (fh0,fc0)
    lstm_rec5<false, true, true><<<rgrid, rblk, 0, stream>>>(
        dU0, db0i, db0h, (const _Float16*)nullptr, fh0, fc0, Y, fh0, fc0, Tlen);
    // 6) XP = d0 @ dec_Wih1^T (permuted)
    gemm_k128<true, true, false><<<gXP, blk, 0, stream>>>((const void*)Y, dW1, (const float*)nullptr, (void*)XP, Mrows, G4);
    // 7) dec L1: init (fh1,fc1)
    lstm_rec5<true, true, true><<<rgrid, rblk, 0, stream>>>(
        dU1, db1i, db1h, XP, fh1, fc1, Y, fh1, fc1, Tlen);
    // 8) out = d1 @ out_W^T + out_b (f32 -> d_out)
    gemm_k128<true, false, true><<<gOut, blk, 0, stream>>>((const void*)Y, oW, ob, d_out, Mrows, Hd);
}

// Round 8
// 5939.305 us; speedup vs baseline: 1.4960x; 1.0138x over previous
//
#include <hip/hip_runtime.h>
#include <cstdint>
#include <cstddef>

typedef float    float4v __attribute__((ext_vector_type(4)));
typedef _Float16 f16x4   __attribute__((ext_vector_type(4)));
typedef _Float16 f16x8   __attribute__((ext_vector_type(8)));

#define DI __device__ __forceinline__

static const int Bsz = 64, Tlen = 2048, Hd = 128, G4 = 512;  // 4H=512
static const int Mrows = Bsz * Tlen;                          // 131072
static const int HSTR = 144;   // H row stride (f16): 0 bank conflicts, validated R7

DI float sigf_fast(float x) {
    float e = __builtin_amdgcn_exp2f(-1.442695041f * x);
    return __builtin_amdgcn_rcpf(1.f + e);
}
DI float tanhf_fast(float x) {
    float e = __builtin_amdgcn_exp2f(-2.885390082f * x);
    return 2.f * __builtin_amdgcn_rcpf(1.f + e) - 1.f;
}

// LDS-only barrier: no vmcnt drain (validated R5, -24%).
DI void lds_barrier() {
    asm volatile("s_waitcnt lgkmcnt(0)\n\ts_barrier" ::: "memory");
}

// Pin a 128-bit fragment in VGPRs: the empty asm "modifies" the value, so the
// compiler cannot rematerialize it by re-loading U from global every step.
// (R3-R7 all had VGPR_Count < sizeof(af): compiler was re-fetching Whh from
// HBM each timestep -> FETCH_SIZE 66.6 GB/dispatch vs 0.13 GB of inputs.)
DI void pin(f16x8& v) {
    float4v t = __builtin_bit_cast(float4v, v);
    asm volatile("" : "+v"(t));
    v = __builtin_bit_cast(f16x8, t);
}

// load 8 consecutive f32, convert to f16x8
DI f16x8 cvt8(const float* p) {
    float4v u = *(const float4v*)p;
    float4v w = *(const float4v*)(p + 4);
    f16x8 o;
    o[0] = (_Float16)u[0]; o[1] = (_Float16)u[1]; o[2] = (_Float16)u[2]; o[3] = (_Float16)u[3];
    o[4] = (_Float16)w[0]; o[5] = (_Float16)w[1]; o[6] = (_Float16)w[2]; o[7] = (_Float16)w[3];
    return o;
}

// ---------------------------------------------------------------------------
// GEMM: C[M,N] = A[M,128] @ Wsel^T (+bias). MFMA f32_16x16x32_f16.
// n-block fastest -> A-tile read once from HBM, re-hit in L2.
// PERM: col n pulls W row ((n&3)*128 + (n>>2)) -> XP gate-interleaved (4j+q).
// Validated R4-R7.
// ---------------------------------------------------------------------------
template <bool A_F16, bool PERM, bool OUT_F32>
__global__ __launch_bounds__(256) void gemm_k128(
    const void* __restrict__ Av, const float* __restrict__ W,
    const float* __restrict__ bias, void* __restrict__ Cout, int M, int N)
{
    const int lane = threadIdx.x & 63, wave = threadIdx.x >> 6;
    const int m0 = blockIdx.y * 64 + wave * 16;
    const int n0 = blockIdx.x * 64;
    const int r15 = lane & 15, kg = lane >> 4;   // kg in 0..3

    f16x8 a[4];
    if (A_F16) {
        const f16x8* Ar = (const f16x8*)((const _Float16*)Av + (size_t)(m0 + r15) * 128);
#pragma unroll
        for (int kt = 0; kt < 4; kt++) a[kt] = Ar[kt * 4 + kg];
    } else {
        const float* Ar = (const float*)Av + (size_t)(m0 + r15) * 128;
#pragma unroll
        for (int kt = 0; kt < 4; kt++) a[kt] = cvt8(Ar + kt * 32 + kg * 8);
    }

    f16x8 bfrg[4][4];
#pragma unroll
    for (int nt = 0; nt < 4; nt++) {
        int n = n0 + nt * 16 + r15;
        int wrow = PERM ? ((n & 3) * 128 + (n >> 2)) : n;
        const float* Wr = W + (size_t)wrow * 128;
#pragma unroll
        for (int kt = 0; kt < 4; kt++) bfrg[nt][kt] = cvt8(Wr + kt * 32 + kg * 8);
    }

    float4v acc[4] = {};
#pragma unroll
    for (int kt = 0; kt < 4; kt++)
#pragma unroll
        for (int nt = 0; nt < 4; nt++)
            acc[nt] = __builtin_amdgcn_mfma_f32_16x16x32_f16(a[kt], bfrg[nt][kt], acc[nt], 0, 0, 0);

#pragma unroll
    for (int nt = 0; nt < 4; nt++) {
        int n = n0 + nt * 16 + r15;
        float bv = bias ? bias[n] : 0.f;
#pragma unroll
        for (int r = 0; r < 4; r++) {
            int m = m0 + kg * 4 + r;
            float v = acc[nt][r] + bv;
            if (OUT_F32) ((float*)Cout)[(size_t)m * N + n] = v;
            else         ((_Float16*)Cout)[(size_t)m * N + n] = (_Float16)v;
        }
    }
}

// ---------------------------------------------------------------------------
// LSTM recurrence v6 = v5 (validated R7) + VGPR-pinned A-fragments.
// 16 WGs x 512 threads (8 waves, 2/SIMD); NB=4 batches/WG.
//   wave w owns j in [16w,16w+16): 4 m-tiles x 4 kc = 16 MFMA/wave.
//   A-frag: tile-row m=col -> Whh row (m&3)*128 + (w*16 + mt*4 + (m>>2)).
//   B replicated: B[n][k] = h[n&3][k] (same-addr LDS broadcast, free).
//   Lane (col=b+4s, quad): acc[mt][q] = gate q of (b, j=w*16+mt*4+quad);
//   own gate-set is mt=s -> one-level select, ONE gate-set per thread.
// ONE lds_barrier/step.
// ---------------------------------------------------------------------------
template <bool HAS_XP, bool WRITE_Y, bool INIT>
__global__ __launch_bounds__(512, 1) void lstm_rec6(
    const float* __restrict__ U,                     // Whh [512,128] f32
    const float* __restrict__ bi, const float* __restrict__ bh,
    const _Float16* __restrict__ XP,                 // [B,T,512] f16 PERMUTED (4j+q)
    const float* __restrict__ ih, const float* __restrict__ ic,
    _Float16* __restrict__ Yout,                     // [B,T,128] f16 or null
    float* __restrict__ fh, float* __restrict__ fc, int T)
{
    const int tid  = threadIdx.x;
    const int lane = tid & 63, w = tid >> 6;         // 8 waves
    const int col  = lane & 15, quad = lane >> 4;
    const int b    = col & 3, s = col >> 2;          // batch, copy id
    const int bglob = blockIdx.x * 4 + b;
    const int j    = w * 16 + s * 4 + quad;          // owned gate-set (unique per thread)

    __shared__ alignas(16) _Float16 Hl[2 * 4 * HSTR];

    // --- static A-frags: tile-row m=col -> Whh row (m&3)*128 + (w*16+mt*4+(m>>2)) ---
    f16x8 af[4][4];
#pragma unroll
    for (int mt = 0; mt < 4; mt++) {
        int urow = (col & 3) * 128 + (w * 16 + mt * 4 + (col >> 2));
        const float* ur = U + (size_t)urow * 128;
#pragma unroll
        for (int kc = 0; kc < 4; kc++)
            af[mt][kc] = cvt8(ur + kc * 32 + quad * 8);
    }
    // Pin: forbid rematerialization (per-step HBM reload) of the weights.
#pragma unroll
    for (int mt = 0; mt < 4; mt++)
#pragma unroll
        for (int kc = 0; kc < 4; kc++)
            pin(af[mt][kc]);

    float bq[4];
#pragma unroll
    for (int q = 0; q < 4; q++) bq[q] = bi[q * 128 + j] + bh[q * 128 + j];

    float c = 0.f, hv = 0.f;
    if (INIT) {
        c  = ic[(size_t)bglob * 128 + j];
        hv = ih[(size_t)bglob * 128 + j];
    }
    Hl[b * HSTR + j] = (_Float16)hv;                 // every (b,j) covered exactly once
    __syncthreads();

    const _Float16* xb = HAS_XP ? XP + ((size_t)bglob * T) * 512 + 4 * j : nullptr;
    f16x4 xp = {};
    if (HAS_XP) xp = *(const f16x4*)xb;

    int cur = 0;
    for (int t = 0; t < T; t++) {
        // prefetch xp(t+1): in flight across the whole step
        f16x4 xpn = {};
        if (HAS_XP && (t + 1 < T)) xpn = *(const f16x4*)(xb + (size_t)(t + 1) * 512);

        // ---- MFMA phase: B replicated by batch (row b for all 4 copies) ----
        const _Float16* Hc = Hl + cur * (4 * HSTR);
        f16x8 bf[4];
#pragma unroll
        for (int kc = 0; kc < 4; kc++)
            bf[kc] = *(const f16x8*)(Hc + b * HSTR + kc * 32 + quad * 8);

        float4v acc[4] = {};
#pragma unroll
        for (int kc = 0; kc < 4; kc++)
#pragma unroll
            for (int mt = 0; mt < 4; mt++)
                acc[mt] = __builtin_amdgcn_mfma_f32_16x16x32_f16(af[mt][kc], bf[kc], acc[mt], 0, 0, 0);

        // ---- select this lane's gate-set: mt = s ----
        float4v t0 = (s & 1) ? acc[1] : acc[0];
        float4v t1 = (s & 1) ? acc[3] : acc[2];
        float4v g  = (s & 2) ? t1 : t0;

        // ---- update in registers ----
        float g0 = g[0] + bq[0], g1 = g[1] + bq[1], g2 = g[2] + bq[2], g3 = g[3] + bq[3];
        if (HAS_XP) { g0 += (float)xp[0]; g1 += (float)xp[1]; g2 += (float)xp[2]; g3 += (float)xp[3]; }
        float iv = sigf_fast(g0), fv = sigf_fast(g1);
        float gv = tanhf_fast(g2), ov = sigf_fast(g3);
        c  = fv * c + iv * gv;
        hv = ov * tanhf_fast(c);

        Hl[(cur ^ 1) * (4 * HSTR) + b * HSTR + j] = (_Float16)hv;
        if (WRITE_Y)
            Yout[((size_t)bglob * T + t) * 128 + j] = (_Float16)hv;
        lds_barrier();                                // ONE barrier per step

        xp = xpn;
        cur ^= 1;
    }

    fh[(size_t)bglob * 128 + j] = hv;
    fc[(size_t)bglob * 128 + j] = c;
}

// ---------------------------------------------------------------------------
// Host side: 8 stream-ordered launches.
//   ws: XP f16 [131072,512] perm (128MB) | Y f16 [131072,128] (32MB) | finals
// ---------------------------------------------------------------------------
extern "C" void kernel_launch(void* const* d_in, const int* in_sizes, int n_in,
                              void* d_out, int out_size, void* d_ws, size_t ws_size,
                              hipStream_t stream)
{
    const float* x    = (const float*)d_in[0];
    const float* eW0  = (const float*)d_in[1];
    const float* eU0  = (const float*)d_in[2];
    const float* eb0i = (const float*)d_in[3];
    const float* eb0h = (const float*)d_in[4];
    const float* eW1  = (const float*)d_in[5];
    const float* eU1  = (const float*)d_in[6];
    const float* eb1i = (const float*)d_in[7];
    const float* eb1h = (const float*)d_in[8];
    const float* dU0  = (const float*)d_in[10];
    const float* db0i = (const float*)d_in[11];
    const float* db0h = (const float*)d_in[12];
    const float* dW1  = (const float*)d_in[13];
    const float* dU1  = (const float*)d_in[14];
    const float* db1i = (const float*)d_in[15];
    const float* db1h = (const float*)d_in[16];
    const float* oW   = (const float*)d_in[17];
    const float* ob   = (const float*)d_in[18];

    char* ws = (char*)d_ws;
    _Float16* XP = (_Float16*)ws;                               // 134217728 B
    _Float16* Y  = (_Float16*)(ws + 134217728);                 //  33554432 B
    float*    fh0 = (float*)(ws + 167772160);
    float*    fc0 = fh0 + Bsz * Hd;
    float*    fh1 = fc0 + Bsz * Hd;
    float*    fc1 = fh1 + Bsz * Hd;

    dim3 blk(256);
    dim3 gXP(G4 / 64, Mrows / 64);    // (8, 2048): n-block fastest
    dim3 gOut(Hd / 64, Mrows / 64);   // (2, 2048)
    dim3 rgrid(Bsz / 4);              // 16
    dim3 rblk(512);

    // 1) XP = x @ enc_Wih0^T (permuted, f16)
    gemm_k128<false, true, false><<<gXP, blk, 0, stream>>>((const void*)x, eW0, (const float*)nullptr, (void*)XP, Mrows, G4);
    // 2) enc L0
    lstm_rec6<true, true, false><<<rgrid, rblk, 0, stream>>>(
        eU0, eb0i, eb0h, XP, (const float*)nullptr, (const float*)nullptr, Y, fh0, fc0, Tlen);
    // 3) XP = y0 @ enc_Wih1^T (permuted)
    gemm_k128<true, true, false><<<gXP, blk, 0, stream>>>((const void*)Y, eW1, (const float*)nullptr, (void*)XP, Mrows, G4);
    // 4) enc L1 (y discarded)
    lstm_rec6<true, false, false><<<rgrid, rblk, 0, stream>>>(
        eU1, eb1i, eb1h, XP, (const float*)nullptr, (const float*)nullptr, (_Float16*)nullptr, fh1, fc1, Tlen);
    // 5) dec L0: zeros input, init (fh0,fc0)
    lstm_rec6<false, true, true><<<rgrid, rblk, 0, stream>>>(
        dU0, db0i, db0h, (const _Float16*)nullptr, fh0, fc0, Y, fh0, fc0, Tlen);
    // 6) XP = d0 @ dec_Wih1^T (permuted)
    gemm_k128<true, true, false><<<gXP, blk, 0, stream>>>((const void*)Y, dW1, (const float*)nullptr, (void*)XP, Mrows, G4);
    // 7) dec L1: init (fh1,fc1)
    lstm_rec6<true, true, true><<<rgrid, rblk, 0, stream>>>(
        dU1, db1i, db1h, XP, fh1, fc1, Y, fh1, fc1, Tlen);
    // 8) out = d1 @ out_W^T + out_b (f32 -> d_out)
    gemm_k128<true, false, true><<<gOut, blk, 0, stream>>>((const void*)Y, oW, ob, d_out, Mrows, Hd);
}